// Round 7
// baseline (104.373 us; speedup 1.0000x reference)
//
#include <hip/hip_runtime.h>
#include <math.h>

#define NB 64
#define NN 512
#define ND 128

typedef __attribute__((ext_vector_type(8))) short short8;
typedef __attribute__((ext_vector_type(4))) float f32x4;

__device__ inline unsigned short f2bf(float x) {
    unsigned int u = __float_as_uint(x);
    return (unsigned short)((u + 0x7FFFu + ((u >> 16) & 1u)) >> 16);
}
__device__ inline float bf2f(unsigned short u) {
    return __uint_as_float(((unsigned int)u) << 16);
}

// One block per batch. Whole pipeline in-LDS: W transpose -> MFMA proj ->
// qk/qsum -> agg -> norm -> softmax -> attn + context. No global scratch.
__global__ __launch_bounds__(512, 1) void ga_one(
    const float* __restrict__ aq, const float* __restrict__ mask,
    const float* __restrict__ Wq, const float* __restrict__ bq,
    const float* __restrict__ Wk, const float* __restrict__ bk,
    float* __restrict__ out_attn, float* __restrict__ out_ctx)
{
    // 512 rows x 136-pitch bf16 k-store; W-stage [128][268] overlays it (freed
    // before first k-store via the post-extraction barrier).
    __shared__ __align__(16) unsigned char kv_raw[512 * 136 * 2];   // 139264 B
    __shared__ __align__(16) unsigned char ab_raw[32 * 136 * 2];    // 8704 B; phase-2 scratch overlay
    __shared__ float mask_s[512];
    __shared__ float agg_s[512];
    __shared__ float qkp[4][512];
    __shared__ float qs[128];
    __shared__ float red2[16];
    __shared__ float bcast[4];

    unsigned short (*kv)[136]  = (unsigned short (*)[136])kv_raw;
    unsigned short (*wst)[268] = (unsigned short (*)[268])kv_raw;   // 68608 B used
    unsigned short (*ab)[136]  = (unsigned short (*)[136])ab_raw;
    float (*ctx_part)[128]     = (float (*)[128])ab_raw;            // phase D overlay

    const int b    = blockIdx.x;
    const int t    = threadIdx.x;
    const int w    = t >> 6, lane = t & 63;
    const int quad = lane >> 4, l16 = lane & 15;
    const bool isq = (w < 4);
    const int cb   = (w & 3) * 32;            // this wave's 32-col d-slice

    // ---- stage W (fp32 coalesced) -> bf16 wst[k][c], c: 0..127=Wq, 128..255=Wk ----
    {
        const float4* srcq = (const float4*)Wq;
        const float4* srck = (const float4*)Wk;
        #pragma unroll
        for (int i = 0; i < 8; i++) {
            const int idx = t + 512*i;            // 4096 float4
            const int k = idx >> 5, c4 = idx & 31;
            float4 v = srcq[idx];
            ushort4 o;
            o.x = f2bf(v.x); o.y = f2bf(v.y); o.z = f2bf(v.z); o.w = f2bf(v.w);
            *(ushort4*)&wst[k][c4*4] = o;
            v = srck[idx];
            o.x = f2bf(v.x); o.y = f2bf(v.y); o.z = f2bf(v.z); o.w = f2bf(v.w);
            *(ushort4*)&wst[k][128 + c4*4] = o;
        }
        mask_s[t] = mask[(size_t)b*NN + t];
    }
    __syncthreads();

    // ---- extract this wave's B fragments (2 nt x 4 kc) ----
    short8 bfr[2][4];
    {
        const int colbase = cb + (isq ? 0 : 128);
        #pragma unroll
        for (int nt = 0; nt < 2; nt++)
            #pragma unroll
            for (int kc = 0; kc < 4; kc++) {
                short8 v;
                #pragma unroll
                for (int j = 0; j < 8; j++)
                    v[j] = (short)wst[kc*32 + quad*8 + j][colbase + nt*16 + l16];
                bfr[nt][kc] = v;
            }
    }
    float bv[2];
    #pragma unroll
    for (int nt = 0; nt < 2; nt++)
        bv[nt] = isq ? bq[cb + nt*16 + l16] : bk[cb + nt*16 + l16];
    __syncthreads();          // W region now dead; kv stores may begin

    float s0 = 0.f, s1 = 0.f;     // qsum accumulators (q-waves)

    // preload sub-chunk 0
    float4 pre0, pre1;
    {
        const float4* asrc = (const float4*)(aq + (size_t)b*NN*ND);
        pre0 = asrc[t]; pre1 = asrc[t + 512];
    }

    for (int sc = 0; sc < 16; sc++) {
        // store preloaded A (32 rows x 128) as bf16
        {
            int idx = t, row = idx >> 5, c4 = idx & 31;
            ushort4 o;
            o.x = f2bf(pre0.x); o.y = f2bf(pre0.y); o.z = f2bf(pre0.z); o.w = f2bf(pre0.w);
            *(ushort4*)&ab[row][c4*4] = o;
            idx = t + 512; row = idx >> 5; c4 = idx & 31;
            o.x = f2bf(pre1.x); o.y = f2bf(pre1.y); o.z = f2bf(pre1.z); o.w = f2bf(pre1.w);
            *(ushort4*)&ab[row][c4*4] = o;
        }
        __syncthreads();
        if (sc < 15) {        // prefetch next chunk under MFMA
            const float4* asrc = (const float4*)(aq + ((size_t)b*NN + (sc+1)*32)*ND);
            pre0 = asrc[t]; pre1 = asrc[t + 512];
        }

        f32x4 acc[2][2];
        #pragma unroll
        for (int m = 0; m < 2; m++)
            #pragma unroll
            for (int nt = 0; nt < 2; nt++)
                acc[m][nt] = (f32x4){0.f, 0.f, 0.f, 0.f};

        #pragma unroll
        for (int m = 0; m < 2; m++) {
            short8 afr[4];
            #pragma unroll
            for (int kc = 0; kc < 4; kc++)
                afr[kc] = *(const short8*)&ab[m*16 + l16][kc*32 + quad*8];
            #pragma unroll
            for (int nt = 0; nt < 2; nt++)
                #pragma unroll
                for (int kc = 0; kc < 4; kc++)
                    acc[m][nt] = __builtin_amdgcn_mfma_f32_16x16x32_bf16(
                        afr[kc], bfr[nt][kc], acc[m][nt], 0, 0, 0);
        }
        #pragma unroll
        for (int m = 0; m < 2; m++)
            #pragma unroll
            for (int nt = 0; nt < 2; nt++)
                #pragma unroll
                for (int r = 0; r < 4; r++)
                    acc[m][nt][r] += bv[nt];

        if (!isq) {   // k-waves: store k rows to LDS
            #pragma unroll
            for (int m = 0; m < 2; m++)
                #pragma unroll
                for (int r = 0; r < 4; r++) {
                    const int row = sc*32 + m*16 + quad*4 + r;
                    kv[row][cb + l16]      = f2bf(acc[m][0][r]);
                    kv[row][cb + 16 + l16] = f2bf(acc[m][1][r]);
                }
        }
        __syncthreads();   // k visible; A consumed -> next staging safe

        if (isq) {    // q-waves: qk partial over this wave's 32 cols + qsum
            #pragma unroll
            for (int m = 0; m < 2; m++) {
                float p[4];
                #pragma unroll
                for (int r = 0; r < 4; r++) {
                    const int row = sc*32 + m*16 + quad*4 + r;
                    p[r] = acc[m][0][r]*bf2f(kv[row][cb + l16])
                         + acc[m][1][r]*bf2f(kv[row][cb + 16 + l16]);
                }
                #pragma unroll
                for (int off = 1; off <= 8; off <<= 1)
                    #pragma unroll
                    for (int r = 0; r < 4; r++)
                        p[r] += __shfl_xor(p[r], off);
                if (l16 == 0)
                    #pragma unroll
                    for (int r = 0; r < 4; r++)
                        qkp[w][sc*32 + m*16 + quad*4 + r] = p[r];
                #pragma unroll
                for (int r = 0; r < 4; r++) {
                    const int row = sc*32 + m*16 + quad*4 + r;
                    const float mk = mask_s[row];
                    s0 += mk * acc[m][0][r];
                    s1 += mk * acc[m][1][r];
                }
            }
        }
    }

    // qsum: reduce over quads (butterfly leaves sum in all lanes)
    if (isq) {
        s0 += __shfl_xor(s0, 16); s0 += __shfl_xor(s0, 32);
        s1 += __shfl_xor(s1, 16); s1 += __shfl_xor(s1, 32);
        if (lane < 16) { qs[cb + lane] = s0; qs[cb + 16 + lane] = s1; }
    }
    __syncthreads();

    // ---- Phase A: agg[n] = mask*(k.qsum - qk); 16 lanes/row, 4 rows/pass ----
    {
        float qsf[8];
        #pragma unroll
        for (int j = 0; j < 8; j++) qsf[j] = qs[l16*8 + j];
        for (int i0 = 0; i0 < 64; i0 += 4) {
            const int n = w*64 + i0 + quad;
            const short8 kr = *(const short8*)&kv[n][l16*8];
            float p = 0.f;
            #pragma unroll
            for (int j = 0; j < 8; j++)
                p += bf2f((unsigned short)kr[j]) * qsf[j];
            #pragma unroll
            for (int off = 1; off <= 8; off <<= 1) p += __shfl_xor(p, off);
            if (l16 == 0) {
                const float qkv = qkp[0][n] + qkp[1][n] + qkp[2][n] + qkp[3][n];
                agg_s[n] = mask_s[n] * (p - qkv);
            }
        }
    }
    __syncthreads();

    // ---- Phase B: norm2 + masked max (thread t owns row t) ----
    const float v  = agg_s[t];
    const bool um  = mask_s[t] != 0.f;
    float sq = v * v;
    float mx = um ? v : -3.0e38f;
    #pragma unroll
    for (int off = 1; off <= 32; off <<= 1) {
        sq += __shfl_xor(sq, off);
        mx = fmaxf(mx, __shfl_xor(mx, off));
    }
    if (lane == 0) { red2[w] = sq; red2[8 + w] = mx; }
    __syncthreads();
    if (t == 0) {
        float s = 0.f, m = -3.0e38f;
        #pragma unroll
        for (int i = 0; i < 8; i++) { s += red2[i]; m = fmaxf(m, red2[8 + i]); }
        bcast[0] = sqrtf(s);
        bcast[1] = m;
    }
    __syncthreads();
    const float nrm = bcast[0];
    const float M   = bcast[1];

    // ---- Phase C: masked exp + Z ----
    const float e = um ? expf((v - M) / nrm) : 0.f;
    agg_s[t] = e;                 // own slot only
    float z = e;
    #pragma unroll
    for (int off = 1; off <= 32; off <<= 1) z += __shfl_xor(z, off);
    if (lane == 0) red2[w] = z;
    __syncthreads();
    if (t == 0) {
        float s = 0.f;
        #pragma unroll
        for (int i = 0; i < 8; i++) s += red2[i];
        bcast[2] = s;
    }
    __syncthreads();
    const float Z = bcast[2];
    out_attn[(size_t)b*NN + t] = e / Z;

    // ---- Phase D: context (128 cols x 4 row-groups) ----
    const int col = t & 127, g = t >> 7;
    float a = 0.f;
    for (int n = g; n < NN; n += 4)
        a += agg_s[n] * bf2f(kv[n][col]);
    ctx_part[g][col] = a;
    __syncthreads();
    if (t < 128)
        out_ctx[(size_t)b*ND + t] =
            (ctx_part[0][t] + ctx_part[1][t] + ctx_part[2][t] + ctx_part[3][t]) / Z;
}

extern "C" void kernel_launch(void* const* d_in, const int* in_sizes, int n_in,
                              void* d_out, int out_size, void* d_ws, size_t ws_size,
                              hipStream_t stream)
{
    const float* aq   = (const float*)d_in[0];
    const float* mask = (const float*)d_in[1];
    const float* Wq   = (const float*)d_in[2];
    const float* bq   = (const float*)d_in[3];
    const float* Wk   = (const float*)d_in[4];
    const float* bk   = (const float*)d_in[5];

    float* out_attn = (float*)d_out;
    float* out_ctx  = (float*)d_out + NB*NN;

    ga_one<<<dim3(NB), dim3(512), 0, stream>>>(aq, mask, Wq, bq, Wk, bk,
                                               out_attn, out_ctx);
}